// Round 9
// baseline (541.883 us; speedup 1.0000x reference)
//
#include <hip/hip_runtime.h>
#include <hip/hip_bf16.h>

// GCN: 5 x (GEMM 64x64 -> CSR gather + bias/ReLU/BN/residual) -> mean-pool -> MLP head.
// R2: hierarchical scan. R3: unrolled gather. R4: bf16 T. R5: norm folded into GEMM,
//     padded branch-free 16-wide gather. R6: 2-phase bucket-partition CSR build.
// R7: GEMM thread=(row,quarter) -> wave-uniform W s_loads, 76% occupancy.
// R8 (REVERTED): pair-packed gather halved in-flight loads -> regressed. Lesson:
//     aggregate is MLP-bound (Little's law), not issue-slot-bound.
// R9: two nodes per wave, co-issued 16-edge batches -> 32 gathers in flight/wave.

#define NNODES 100000
#define NEDGES 1000000
#define NGRAPH 64
#define HDIM 64
#define SCAN_CHUNK 1024
#define PADM 16      // bucket pad multiple for aggregate's 16-wide batches
#define EPB 4096     // edges per block in partition phases

typedef unsigned int uint32;
typedef unsigned short ushort16;

__device__ __forceinline__ float bf16_to_f32(ushort16 u) {
    return __uint_as_float(((uint32)u) << 16);
}
__device__ __forceinline__ uint32 pack_bf16x2(float lo, float hi) {
    __hip_bfloat16 l = __float2bfloat16(lo);
    __hip_bfloat16 h = __float2bfloat16(hi);
    return ((uint32)(*(ushort16*)&h) << 16) | (uint32)(*(ushort16*)&l);
}
__device__ __forceinline__ int padded(int c) { return (c + PADM - 1) & ~(PADM - 1); }

// ---------------- zero ----------------
__global__ void zero_kernel(int* __restrict__ p, int n) {
    int i = blockIdx.x * 256 + threadIdx.x;
    if (i < n) p[i] = 0;
}

// ---------------- A1: bucket histogram (bucket = dst>>8) ----------------
__global__ __launch_bounds__(256) void bucket_hist_kernel(const int* __restrict__ ei,
                                                          int* __restrict__ bhist,
                                                          int E, int nbuck) {
    __shared__ int h[512];
    for (int i = threadIdx.x; i < nbuck; i += 256) h[i] = 0;
    __syncthreads();
    int base = blockIdx.x * EPB;
    int end = base + EPB; if (end > E) end = E;
    for (int e = base + threadIdx.x; e < end; e += 256)
        atomicAdd(&h[ei[E + e] >> 8], 1);
    __syncthreads();
    for (int i = threadIdx.x; i < nbuck; i += 256)
        if (h[i]) atomicAdd(&bhist[i], h[i]);
}

// ---------------- bucket scan: bases + cursors ----------------
__global__ __launch_bounds__(512) void bucket_scan_kernel(const int* __restrict__ bhist,
                                                          int* __restrict__ bbase,
                                                          int* __restrict__ bcursor,
                                                          int nbuck) {
    __shared__ int sh[512];
    int t = threadIdx.x;
    sh[t] = (t < nbuck) ? bhist[t] : 0;
    __syncthreads();
    for (int off = 1; off < 512; off <<= 1) {
        int v = (t >= off) ? sh[t - off] : 0;
        __syncthreads();
        sh[t] += v;
        __syncthreads();
    }
    int ex = (t == 0) ? 0 : sh[t - 1];
    if (t < nbuck) { bbase[t] = ex; bcursor[t] = ex; }
    if (t == nbuck) bbase[t] = sh[nbuck - 1];   // = E
}

// ------- A2: partition edges into bucket-contiguous packed ((d&255)<<17 | src) ---------
__global__ __launch_bounds__(256) void partition_kernel(const int* __restrict__ ei,
                                                        int* __restrict__ bcursor,
                                                        int* __restrict__ barr,
                                                        int E, int nbuck) {
    __shared__ int h[512];
    __shared__ int lbase[512];
    for (int i = threadIdx.x; i < nbuck; i += 256) h[i] = 0;
    __syncthreads();
    int base = blockIdx.x * EPB;
    int end = base + EPB; if (end > E) end = E;
    for (int e = base + threadIdx.x; e < end; e += 256)
        atomicAdd(&h[ei[E + e] >> 8], 1);
    __syncthreads();
    for (int i = threadIdx.x; i < nbuck; i += 256) {
        int c = h[i];
        lbase[i] = c ? atomicAdd(&bcursor[i], c) : 0;
        h[i] = 0;   // reuse as local cursor
    }
    __syncthreads();
    for (int e = base + threadIdx.x; e < end; e += 256) {
        int s = ei[e];
        int d = ei[E + e];
        int b = d >> 8;
        int r = atomicAdd(&h[b], 1);
        barr[lbase[b] + r] = ((d & 255) << 17) | s;
    }
}

// ---------------- B0: per-bucket node degrees (dense write, LDS hist) ------------------
__global__ __launch_bounds__(256) void degree_kernel(const int* __restrict__ barr,
                                                     const int* __restrict__ bbase,
                                                     int* __restrict__ counts, int N) {
    __shared__ int h[256];
    h[threadIdx.x] = 0;
    __syncthreads();
    int b = blockIdx.x;
    int s0 = bbase[b], s1 = bbase[b + 1];
    for (int e = s0 + threadIdx.x; e < s1; e += 256)
        atomicAdd(&h[barr[e] >> 17], 1);
    __syncthreads();
    int node = (b << 8) + threadIdx.x;
    if (node < N) counts[node] = h[threadIdx.x];
}

// ---------------- scan level 1: per-block partial sums of PADDED counts ---------------
__global__ __launch_bounds__(256) void bsum_kernel(const int* __restrict__ counts,
                                                   int* __restrict__ bsums, int N) {
    __shared__ int ws[4];
    int base = blockIdx.x * SCAN_CHUNK + threadIdx.x * 4;
    int s = 0;
    if (base + 3 < N) {
        int4 c = *(const int4*)(counts + base);
        s = padded(c.x) + padded(c.y) + padded(c.z) + padded(c.w);
    } else {
        for (int k = 0; k < 4 && base + k < N; ++k) s += padded(counts[base + k]);
    }
    for (int off = 32; off > 0; off >>= 1) s += __shfl_down(s, off, 64);
    int wid = threadIdx.x >> 6;
    if ((threadIdx.x & 63) == 0) ws[wid] = s;
    __syncthreads();
    if (threadIdx.x == 0) bsums[blockIdx.x] = ws[0] + ws[1] + ws[2] + ws[3];
}

// ---------------- scan level 2 ----------------
__global__ __launch_bounds__(256) void bscan_kernel(int* __restrict__ bsums, int nb,
                                                    int* __restrict__ row_ptr, int N) {
    __shared__ int sh[256];
    int t = threadIdx.x;
    sh[t] = (t < nb) ? bsums[t] : 0;
    __syncthreads();
    for (int off = 1; off < 256; off <<= 1) {
        int v = (t >= off) ? sh[t - off] : 0;
        __syncthreads();
        sh[t] += v;
        __syncthreads();
    }
    if (t < nb) bsums[t] = (t == 0) ? 0 : sh[t - 1];
    if (t == 255) row_ptr[N] = sh[255];   // total padded entries
}

// ---------------- scan level 3: row_ptr (padded) + dinv ----------------
__global__ __launch_bounds__(256) void scan_apply_kernel(
    const int* __restrict__ counts, const int* __restrict__ bsums,
    int* __restrict__ row_ptr, float* __restrict__ dinv, int N) {
    __shared__ int wsum[4];
    int t = threadIdx.x;
    int lane = t & 63, wid = t >> 6;
    int base = blockIdx.x * SCAN_CHUNK + t * 4;
    int c0 = 0, c1 = 0, c2 = 0, c3 = 0;
    if (base + 3 < N) {
        int4 c = *(const int4*)(counts + base);
        c0 = c.x; c1 = c.y; c2 = c.z; c3 = c.w;
    } else if (base < N) {
        c0 = counts[base];
        if (base + 1 < N) c1 = counts[base + 1];
        if (base + 2 < N) c2 = counts[base + 2];
    }
    int p0 = padded(c0), p1 = padded(c1), p2 = padded(c2), p3 = padded(c3);
    int tsum = p0 + p1 + p2 + p3;
    int incl = tsum;
    for (int off = 1; off < 64; off <<= 1) {
        int v = __shfl_up(incl, off, 64);
        if (lane >= off) incl += v;
    }
    if (lane == 63) wsum[wid] = incl;
    __syncthreads();
    int woff = 0;
    for (int w = 0; w < wid; ++w) woff += wsum[w];
    int off0 = bsums[blockIdx.x] + woff + (incl - tsum);
    if (base + 3 < N) {
        int4 rp; rp.x = off0; rp.y = off0 + p0; rp.z = off0 + p0 + p1; rp.w = off0 + p0 + p1 + p2;
        *(int4*)(row_ptr + base) = rp;
        float4 dv;
        dv.x = rsqrtf((float)(c0 + 1)); dv.y = rsqrtf((float)(c1 + 1));
        dv.z = rsqrtf((float)(c2 + 1)); dv.w = rsqrtf((float)(c3 + 1));
        *(float4*)(dinv + base) = dv;
    } else if (base < N) {
        int run = off0;
        int cs[4] = {c0, c1, c2, c3};
        for (int k = 0; k < 4 && base + k < N; ++k) {
            row_ptr[base + k] = run;
            dinv[base + k] = rsqrtf((float)(cs[k] + 1));
            run += padded(cs[k]);
        }
    }
}

// ---------------- B1: per-bucket counting-sort into csr + sentinel padding -------------
__global__ __launch_bounds__(256) void fill_kernel(const int* __restrict__ barr,
                                                   const int* __restrict__ bbase,
                                                   const int* __restrict__ row_ptr,
                                                   int* __restrict__ csr, int N) {
    __shared__ int rbase[257];
    __shared__ int cur[256];
    int b = blockIdx.x;
    int n0 = b << 8;
    int nn = N - n0; if (nn > 256) nn = 256;
    int t = threadIdx.x;
    if (t < nn) { rbase[t] = row_ptr[n0 + t]; cur[t] = 0; }
    if (t == 0) rbase[nn] = row_ptr[n0 + nn];
    __syncthreads();
    int s0 = bbase[b], s1 = bbase[b + 1];
    for (int e = s0 + t; e < s1; e += 256) {
        int ed = barr[e];
        int d = ed >> 17;
        int r = atomicAdd(&cur[d], 1);
        csr[rbase[d] + r] = ed & 0x1FFFF;
    }
    __syncthreads();
    if (t < nn) {
        int p = rbase[t] + cur[t];
        int pe = rbase[t + 1];
        for (; p < pe; ++p) csr[p] = N;   // sentinel -> zero row Tb[N]
    }
}

// ------- GEMM: T'(bf16) = dinv[row] * (A @ W); thread=(row, quarter=waveId) ------------
__global__ __launch_bounds__(256) void gemm64_kernel(const float* __restrict__ A,
                                                     const float* __restrict__ W,
                                                     const float* __restrict__ dinv,
                                                     ushort16* __restrict__ Tb, int N) {
    int lane = threadIdx.x & 63;
    int q = __builtin_amdgcn_readfirstlane(threadIdx.x >> 6);   // wave-uniform quarter
    int row = blockIdx.x * 64 + lane;
    if (row >= N) return;
    const float4* arow = (const float4*)(A + (size_t)row * HDIM);
    const float* Wq = W + q * 16;
    float acc[16];
#pragma unroll
    for (int j = 0; j < 16; ++j) acc[j] = 0.f;
#pragma unroll 4
    for (int k4 = 0; k4 < 16; ++k4) {
        float4 a4 = arow[k4];
        const float* w0 = Wq + (k4 * 4) * HDIM;
#pragma unroll
        for (int j = 0; j < 16; ++j) acc[j] = fmaf(a4.x, w0[j], acc[j]);
#pragma unroll
        for (int j = 0; j < 16; ++j) acc[j] = fmaf(a4.y, w0[HDIM + j], acc[j]);
#pragma unroll
        for (int j = 0; j < 16; ++j) acc[j] = fmaf(a4.z, w0[2 * HDIM + j], acc[j]);
#pragma unroll
        for (int j = 0; j < 16; ++j) acc[j] = fmaf(a4.w, w0[3 * HDIM + j], acc[j]);
    }
    float di = dinv[row];
    uint4 o0, o1;
    o0.x = pack_bf16x2(acc[0] * di,  acc[1] * di);
    o0.y = pack_bf16x2(acc[2] * di,  acc[3] * di);
    o0.z = pack_bf16x2(acc[4] * di,  acc[5] * di);
    o0.w = pack_bf16x2(acc[6] * di,  acc[7] * di);
    o1.x = pack_bf16x2(acc[8] * di,  acc[9] * di);
    o1.y = pack_bf16x2(acc[10] * di, acc[11] * di);
    o1.z = pack_bf16x2(acc[12] * di, acc[13] * di);
    o1.w = pack_bf16x2(acc[14] * di, acc[15] * di);
    uint4* orow = (uint4*)(Tb + (size_t)row * HDIM + q * 16);
    orow[0] = o0;
    orow[1] = o1;
}

// 16-edge batch accumulate (lane = feature, ushort gathers)
#define AGG_BATCH(E0, A0, A1, A2, A3)                                     \
    {                                                                     \
        int4 s0 = *(const int4*)(csr + (E0));                             \
        int4 s1 = *(const int4*)(csr + (E0) + 4);                         \
        int4 s2 = *(const int4*)(csr + (E0) + 8);                         \
        int4 s3 = *(const int4*)(csr + (E0) + 12);                        \
        float t0  = bf16_to_f32(Tb[(size_t)s0.x * HDIM + lane]);          \
        float t1  = bf16_to_f32(Tb[(size_t)s0.y * HDIM + lane]);          \
        float t2  = bf16_to_f32(Tb[(size_t)s0.z * HDIM + lane]);          \
        float t3  = bf16_to_f32(Tb[(size_t)s0.w * HDIM + lane]);          \
        float t4  = bf16_to_f32(Tb[(size_t)s1.x * HDIM + lane]);          \
        float t5  = bf16_to_f32(Tb[(size_t)s1.y * HDIM + lane]);          \
        float t6  = bf16_to_f32(Tb[(size_t)s1.z * HDIM + lane]);          \
        float t7  = bf16_to_f32(Tb[(size_t)s1.w * HDIM + lane]);          \
        float t8  = bf16_to_f32(Tb[(size_t)s2.x * HDIM + lane]);          \
        float t9  = bf16_to_f32(Tb[(size_t)s2.y * HDIM + lane]);          \
        float t10 = bf16_to_f32(Tb[(size_t)s2.z * HDIM + lane]);          \
        float t11 = bf16_to_f32(Tb[(size_t)s2.w * HDIM + lane]);          \
        float t12 = bf16_to_f32(Tb[(size_t)s3.x * HDIM + lane]);          \
        float t13 = bf16_to_f32(Tb[(size_t)s3.y * HDIM + lane]);          \
        float t14 = bf16_to_f32(Tb[(size_t)s3.z * HDIM + lane]);          \
        float t15 = bf16_to_f32(Tb[(size_t)s3.w * HDIM + lane]);          \
        A0 += t0 + t4;  A1 += t1 + t5;  A2 += t2 + t6;  A3 += t3 + t7;    \
        A0 += t8 + t12; A1 += t9 + t13; A2 += t10 + t14; A3 += t11 + t15; \
    }

// ------- aggregate: TWO nodes per wave, co-issued batches (32 gathers in flight) -------
__global__ __launch_bounds__(256) void aggregate_kernel(
    const ushort16* __restrict__ Tb, const float* __restrict__ dinv,
    const int* __restrict__ row_ptr, const int* __restrict__ csr,
    const float* __restrict__ bias, const float* __restrict__ gamma,
    const float* __restrict__ beta, const float* __restrict__ mean,
    const float* __restrict__ var,
    float* __restrict__ P, int N, int residual) {
    int wave = (blockIdx.x * 256 + threadIdx.x) >> 6;
    int lane = threadIdx.x & 63;
    int nA = wave * 2;
    if (nA >= N) return;
    int nB = nA + 1;
    bool hasB = nB < N;
    int eA = row_ptr[nA], eA1 = row_ptr[nA + 1];
    int eB = eA1, eB1 = hasB ? row_ptr[nB + 1] : eA1;

    float aA0 = bf16_to_f32(Tb[(size_t)nA * HDIM + lane]);  // self-loop A
    float aA1 = 0.f, aA2 = 0.f, aA3 = 0.f;
    float aB0 = hasB ? bf16_to_f32(Tb[(size_t)nB * HDIM + lane]) : 0.f;
    float aB1 = 0.f, aB2 = 0.f, aB3 = 0.f;

    // co-issued main loop: one 16-batch for each node -> 32 gathers in flight
    while (eA < eA1 && eB < eB1) {
        AGG_BATCH(eA, aA0, aA1, aA2, aA3);
        AGG_BATCH(eB, aB0, aB1, aB2, aB3);
        eA += 16; eB += 16;
    }
    for (; eA < eA1; eA += 16) AGG_BATCH(eA, aA0, aA1, aA2, aA3);
    for (; eB < eB1; eB += 16) AGG_BATCH(eB, aB0, aB1, aB2, aB3);

    float bi = bias[lane];
    float sc = rsqrtf(var[lane] + 1e-5f) * gamma[lane];
    float mn = mean[lane], bt = beta[lane];
    {
        float acc = (aA0 + aA1) + (aA2 + aA3);
        float v = acc * dinv[nA] + bi;
        v = fmaxf(v, 0.f);
        v = (v - mn) * sc + bt;
        if (residual) v += P[(size_t)nA * HDIM + lane];
        P[(size_t)nA * HDIM + lane] = v;
    }
    if (hasB) {
        float acc = (aB0 + aB1) + (aB2 + aB3);
        float v = acc * dinv[nB] + bi;
        v = fmaxf(v, 0.f);
        v = (v - mn) * sc + bt;
        if (residual) v += P[(size_t)nB * HDIM + lane];
        P[(size_t)nB * HDIM + lane] = v;
    }
}

// ---------------- mean-pool ----------------
__global__ __launch_bounds__(256) void pool_kernel(const float* __restrict__ P,
                                                   const int* __restrict__ batch,
                                                   float* __restrict__ gsum,
                                                   float* __restrict__ gcnt, int N) {
    int wave = (blockIdx.x * 256 + threadIdx.x) >> 6;
    int lane = threadIdx.x & 63;
    int start = wave * 64;
    if (start >= N) return;
    int end = start + 64; if (end > N) end = N;
    float acc = 0.f;
    int cur = batch[start];
    int cnt = 0;
    for (int i = start; i < end; ++i) {
        int b = batch[i];
        if (b != cur) {
            atomicAdd(&gsum[cur * HDIM + lane], acc);
            if (lane == 0) atomicAdd(&gcnt[cur], (float)cnt);
            cur = b; acc = 0.f; cnt = 0;
        }
        acc += P[(size_t)i * HDIM + lane];
        cnt++;
    }
    atomicAdd(&gsum[cur * HDIM + lane], acc);
    if (lane == 0) atomicAdd(&gcnt[cur], (float)cnt);
}

// ---------------- MLP head (single block) ----------------
__global__ __launch_bounds__(256) void head_kernel(
    const float* __restrict__ gsum, const float* __restrict__ gcnt,
    const float* __restrict__ hW1, const float* __restrict__ hb1,
    const float* __restrict__ hgam, const float* __restrict__ hbet,
    const float* __restrict__ hm, const float* __restrict__ hv,
    const float* __restrict__ hW2, const float* __restrict__ hb2,
    float* __restrict__ out) {
    __shared__ float g[NGRAPH * HDIM];
    __shared__ float h1[NGRAPH * 32];
    int t = threadIdx.x;
    for (int idx = t; idx < NGRAPH * HDIM; idx += 256) {
        int gi = idx >> 6;
        g[idx] = gsum[idx] / fmaxf(gcnt[gi], 1.f);
    }
    __syncthreads();
    for (int idx = t; idx < NGRAPH * 32; idx += 256) {
        int gi = idx >> 5, j = idx & 31;
        float s = hb1[j];
#pragma unroll
        for (int f = 0; f < HDIM; ++f) s += g[gi * HDIM + f] * hW1[f * 32 + j];
        s = fmaxf(s, 0.f);
        s = (s - hm[j]) * rsqrtf(hv[j] + 1e-5f) * hgam[j] + hbet[j];
        h1[idx] = s;
    }
    __syncthreads();
    if (t < NGRAPH) {
        float s = hb2[0];
#pragma unroll
        for (int j = 0; j < 32; ++j) s += h1[t * 32 + j] * hW2[j];
        out[t] = s;
    }
}

static inline size_t align_up(size_t x) { return (x + 255) & ~(size_t)255; }

extern "C" void kernel_launch(void* const* d_in, const int* in_sizes, int n_in,
                              void* d_out, int out_size, void* d_ws, size_t ws_size,
                              hipStream_t stream) {
    const float* x    = (const float*)d_in[0];
    const int*   ei   = (const int*)d_in[1];
    const int*   batch= (const int*)d_in[2];
    const float* Wc   = (const float*)d_in[3];
    const float* bc   = (const float*)d_in[4];
    const float* bng  = (const float*)d_in[5];
    const float* bnb  = (const float*)d_in[6];
    const float* bnm  = (const float*)d_in[7];
    const float* bnv  = (const float*)d_in[8];
    const float* hW1  = (const float*)d_in[9];
    const float* hb1  = (const float*)d_in[10];
    const float* hgam = (const float*)d_in[11];
    const float* hbet = (const float*)d_in[12];
    const float* hm   = (const float*)d_in[13];
    const float* hv   = (const float*)d_in[14];
    const float* hW2  = (const float*)d_in[15];
    const float* hb2  = (const float*)d_in[16];
    float* out = (float*)d_out;

    const int N = in_sizes[0] / HDIM;   // 100000
    const int E = in_sizes[1] / 2;      // 1000000
    const int nbuck = (N + 255) >> 8;   // 391

    // ---- workspace carve (all 256B aligned) ----
    char* ws = (char*)d_ws;
    size_t off = 0;
    float*    P  = (float*)(ws + off);    off += align_up((size_t)N * HDIM * 4);
    ushort16* Tb = (ushort16*)(ws + off); off += align_up((size_t)(N + 1) * HDIM * 2); // +1 sentinel row
    int*   counts  = (int*)(ws + off);    off += align_up((size_t)N * 4);
    int*   row_ptr = (int*)(ws + off);    off += align_up((size_t)(N + 1) * 4);
    float* dinv    = (float*)(ws + off);  off += align_up((size_t)N * 4);
    int*   bsums   = (int*)(ws + off);    off += align_up(256 * 4);
    int*   bhist   = (int*)(ws + off);    off += align_up(512 * 4);
    int*   bbase   = (int*)(ws + off);    off += align_up(513 * 4);
    int*   bcursor = (int*)(ws + off);    off += align_up(512 * 4);
    float* gsum = (float*)(ws + off);
    float* gcnt = (float*)(ws + off + (size_t)NGRAPH * HDIM * 4);
    off += align_up((size_t)(NGRAPH * HDIM + NGRAPH) * 4);
    int*   barr = (int*)(ws + off);       off += align_up((size_t)E * 4);
    int*   csr  = (int*)(ws + off);       off += align_up(((size_t)E + (size_t)(PADM - 1) * N) * 4);

    int nScanBlocks = (N + SCAN_CHUNK - 1) / SCAN_CHUNK;   // 98
    int nPartBlocks = (E + EPB - 1) / EPB;                 // 245
    int gemmBlocks  = (N + 63) / 64;                       // 1563

    // ---- zero small state ----
    zero_kernel<<<2, 256, 0, stream>>>(bhist, nbuck);
    zero_kernel<<<(NGRAPH * HDIM + NGRAPH + 255) / 256, 256, 0, stream>>>((int*)gsum, NGRAPH * HDIM + NGRAPH);
    zero_kernel<<<1, 256, 0, stream>>>((int*)(Tb + (size_t)N * HDIM), 32);  // sentinel row = 0

    // ---- bucket partition + CSR build ----
    bucket_hist_kernel<<<nPartBlocks, 256, 0, stream>>>(ei, bhist, E, nbuck);
    bucket_scan_kernel<<<1, 512, 0, stream>>>(bhist, bbase, bcursor, nbuck);
    partition_kernel<<<nPartBlocks, 256, 0, stream>>>(ei, bcursor, barr, E, nbuck);
    degree_kernel<<<nbuck, 256, 0, stream>>>(barr, bbase, counts, N);
    bsum_kernel<<<nScanBlocks, 256, 0, stream>>>(counts, bsums, N);
    bscan_kernel<<<1, 256, 0, stream>>>(bsums, nScanBlocks, row_ptr, N);
    scan_apply_kernel<<<nScanBlocks, 256, 0, stream>>>(counts, bsums, row_ptr, dinv, N);
    fill_kernel<<<nbuck, 256, 0, stream>>>(barr, bbase, row_ptr, csr, N);

    // ---- 5 GCN layers ----
    int aggBlocks = (N + 7) / 8;   // 4 waves/block x 2 nodes/wave
    for (int l = 0; l < 5; ++l) {
        const float* in = (l == 0) ? x : P;
        gemm64_kernel<<<gemmBlocks, 256, 0, stream>>>(in, Wc + (size_t)l * HDIM * HDIM, dinv, Tb, N);
        aggregate_kernel<<<aggBlocks, 256, 0, stream>>>(
            Tb, dinv, row_ptr, csr,
            bc + l * HDIM, bng + l * HDIM, bnb + l * HDIM, bnm + l * HDIM, bnv + l * HDIM,
            P, N, (l > 0) ? 1 : 0);
    }

    // ---- pool + head ----
    int poolBlocks = (N + 255) / 256;
    pool_kernel<<<poolBlocks, 256, 0, stream>>>(P, batch, gsum, gcnt, N);
    head_kernel<<<1, 256, 0, stream>>>(gsum, gcnt, hW1, hb1, hgam, hbet, hm, hv, hW2, hb2, out);
}

// Round 10
// 479.437 us; speedup vs baseline: 1.1302x; 1.1302x over previous
//
#include <hip/hip_runtime.h>
#include <hip/hip_bf16.h>

// GCN: 5 x (GEMM 64x64 -> CSR gather + bias/ReLU/BN/residual) -> mean-pool -> MLP head.
// R2: hierarchical scan. R3: unrolled gather. R4: bf16 T. R5: norm folded into GEMM,
//     padded branch-free 16-wide gather. R6: 2-phase bucket-partition CSR build.
// R7: GEMM thread=(row,quarter) -> wave-uniform W s_loads, 76% occupancy.
// R8 (reverted): pair-packed gather halved in-flight loads -> 47us. R9 (reverted):
//     2 nodes/wave doubled VGPR, halved occupancy -> 55us. Lesson: aggregate thruput
//     = waves x inflight/wave; R7 point (1 node/wave, 16 gathers, 20 VGPR, 70% occ)
//     is the optimum. R10: restore R7 aggregate exactly; keep packed barr build.

#define NNODES 100000
#define NEDGES 1000000
#define NGRAPH 64
#define HDIM 64
#define SCAN_CHUNK 1024
#define PADM 16      // bucket pad multiple for aggregate's 16-wide batches
#define EPB 4096     // edges per block in partition phases

typedef unsigned int uint32;
typedef unsigned short ushort16;

__device__ __forceinline__ float bf16_to_f32(ushort16 u) {
    return __uint_as_float(((uint32)u) << 16);
}
__device__ __forceinline__ uint32 pack_bf16x2(float lo, float hi) {
    __hip_bfloat16 l = __float2bfloat16(lo);
    __hip_bfloat16 h = __float2bfloat16(hi);
    return ((uint32)(*(ushort16*)&h) << 16) | (uint32)(*(ushort16*)&l);
}
__device__ __forceinline__ int padded(int c) { return (c + PADM - 1) & ~(PADM - 1); }

// ---------------- zero ----------------
__global__ void zero_kernel(int* __restrict__ p, int n) {
    int i = blockIdx.x * 256 + threadIdx.x;
    if (i < n) p[i] = 0;
}

// ---------------- A1: bucket histogram (bucket = dst>>8) ----------------
__global__ __launch_bounds__(256) void bucket_hist_kernel(const int* __restrict__ ei,
                                                          int* __restrict__ bhist,
                                                          int E, int nbuck) {
    __shared__ int h[512];
    for (int i = threadIdx.x; i < nbuck; i += 256) h[i] = 0;
    __syncthreads();
    int base = blockIdx.x * EPB;
    int end = base + EPB; if (end > E) end = E;
    for (int e = base + threadIdx.x; e < end; e += 256)
        atomicAdd(&h[ei[E + e] >> 8], 1);
    __syncthreads();
    for (int i = threadIdx.x; i < nbuck; i += 256)
        if (h[i]) atomicAdd(&bhist[i], h[i]);
}

// ---------------- bucket scan: bases + cursors ----------------
__global__ __launch_bounds__(512) void bucket_scan_kernel(const int* __restrict__ bhist,
                                                          int* __restrict__ bbase,
                                                          int* __restrict__ bcursor,
                                                          int nbuck) {
    __shared__ int sh[512];
    int t = threadIdx.x;
    sh[t] = (t < nbuck) ? bhist[t] : 0;
    __syncthreads();
    for (int off = 1; off < 512; off <<= 1) {
        int v = (t >= off) ? sh[t - off] : 0;
        __syncthreads();
        sh[t] += v;
        __syncthreads();
    }
    int ex = (t == 0) ? 0 : sh[t - 1];
    if (t < nbuck) { bbase[t] = ex; bcursor[t] = ex; }
    if (t == nbuck) bbase[t] = sh[nbuck - 1];   // = E
}

// ------- A2: partition edges into bucket-contiguous packed ((d&255)<<17 | src) ---------
__global__ __launch_bounds__(256) void partition_kernel(const int* __restrict__ ei,
                                                        int* __restrict__ bcursor,
                                                        int* __restrict__ barr,
                                                        int E, int nbuck) {
    __shared__ int h[512];
    __shared__ int lbase[512];
    for (int i = threadIdx.x; i < nbuck; i += 256) h[i] = 0;
    __syncthreads();
    int base = blockIdx.x * EPB;
    int end = base + EPB; if (end > E) end = E;
    for (int e = base + threadIdx.x; e < end; e += 256)
        atomicAdd(&h[ei[E + e] >> 8], 1);
    __syncthreads();
    for (int i = threadIdx.x; i < nbuck; i += 256) {
        int c = h[i];
        lbase[i] = c ? atomicAdd(&bcursor[i], c) : 0;
        h[i] = 0;   // reuse as local cursor
    }
    __syncthreads();
    for (int e = base + threadIdx.x; e < end; e += 256) {
        int s = ei[e];
        int d = ei[E + e];
        int b = d >> 8;
        int r = atomicAdd(&h[b], 1);
        barr[lbase[b] + r] = ((d & 255) << 17) | s;
    }
}

// ---------------- B0: per-bucket node degrees (dense write, LDS hist) ------------------
__global__ __launch_bounds__(256) void degree_kernel(const int* __restrict__ barr,
                                                     const int* __restrict__ bbase,
                                                     int* __restrict__ counts, int N) {
    __shared__ int h[256];
    h[threadIdx.x] = 0;
    __syncthreads();
    int b = blockIdx.x;
    int s0 = bbase[b], s1 = bbase[b + 1];
    for (int e = s0 + threadIdx.x; e < s1; e += 256)
        atomicAdd(&h[barr[e] >> 17], 1);
    __syncthreads();
    int node = (b << 8) + threadIdx.x;
    if (node < N) counts[node] = h[threadIdx.x];
}

// ---------------- scan level 1: per-block partial sums of PADDED counts ---------------
__global__ __launch_bounds__(256) void bsum_kernel(const int* __restrict__ counts,
                                                   int* __restrict__ bsums, int N) {
    __shared__ int ws[4];
    int base = blockIdx.x * SCAN_CHUNK + threadIdx.x * 4;
    int s = 0;
    if (base + 3 < N) {
        int4 c = *(const int4*)(counts + base);
        s = padded(c.x) + padded(c.y) + padded(c.z) + padded(c.w);
    } else {
        for (int k = 0; k < 4 && base + k < N; ++k) s += padded(counts[base + k]);
    }
    for (int off = 32; off > 0; off >>= 1) s += __shfl_down(s, off, 64);
    int wid = threadIdx.x >> 6;
    if ((threadIdx.x & 63) == 0) ws[wid] = s;
    __syncthreads();
    if (threadIdx.x == 0) bsums[blockIdx.x] = ws[0] + ws[1] + ws[2] + ws[3];
}

// ---------------- scan level 2 ----------------
__global__ __launch_bounds__(256) void bscan_kernel(int* __restrict__ bsums, int nb,
                                                    int* __restrict__ row_ptr, int N) {
    __shared__ int sh[256];
    int t = threadIdx.x;
    sh[t] = (t < nb) ? bsums[t] : 0;
    __syncthreads();
    for (int off = 1; off < 256; off <<= 1) {
        int v = (t >= off) ? sh[t - off] : 0;
        __syncthreads();
        sh[t] += v;
        __syncthreads();
    }
    if (t < nb) bsums[t] = (t == 0) ? 0 : sh[t - 1];
    if (t == 255) row_ptr[N] = sh[255];   // total padded entries
}

// ---------------- scan level 3: row_ptr (padded) + dinv ----------------
__global__ __launch_bounds__(256) void scan_apply_kernel(
    const int* __restrict__ counts, const int* __restrict__ bsums,
    int* __restrict__ row_ptr, float* __restrict__ dinv, int N) {
    __shared__ int wsum[4];
    int t = threadIdx.x;
    int lane = t & 63, wid = t >> 6;
    int base = blockIdx.x * SCAN_CHUNK + t * 4;
    int c0 = 0, c1 = 0, c2 = 0, c3 = 0;
    if (base + 3 < N) {
        int4 c = *(const int4*)(counts + base);
        c0 = c.x; c1 = c.y; c2 = c.z; c3 = c.w;
    } else if (base < N) {
        c0 = counts[base];
        if (base + 1 < N) c1 = counts[base + 1];
        if (base + 2 < N) c2 = counts[base + 2];
    }
    int p0 = padded(c0), p1 = padded(c1), p2 = padded(c2), p3 = padded(c3);
    int tsum = p0 + p1 + p2 + p3;
    int incl = tsum;
    for (int off = 1; off < 64; off <<= 1) {
        int v = __shfl_up(incl, off, 64);
        if (lane >= off) incl += v;
    }
    if (lane == 63) wsum[wid] = incl;
    __syncthreads();
    int woff = 0;
    for (int w = 0; w < wid; ++w) woff += wsum[w];
    int off0 = bsums[blockIdx.x] + woff + (incl - tsum);
    if (base + 3 < N) {
        int4 rp; rp.x = off0; rp.y = off0 + p0; rp.z = off0 + p0 + p1; rp.w = off0 + p0 + p1 + p2;
        *(int4*)(row_ptr + base) = rp;
        float4 dv;
        dv.x = rsqrtf((float)(c0 + 1)); dv.y = rsqrtf((float)(c1 + 1));
        dv.z = rsqrtf((float)(c2 + 1)); dv.w = rsqrtf((float)(c3 + 1));
        *(float4*)(dinv + base) = dv;
    } else if (base < N) {
        int run = off0;
        int cs[4] = {c0, c1, c2, c3};
        for (int k = 0; k < 4 && base + k < N; ++k) {
            row_ptr[base + k] = run;
            dinv[base + k] = rsqrtf((float)(cs[k] + 1));
            run += padded(cs[k]);
        }
    }
}

// ---------------- B1: per-bucket counting-sort into csr + sentinel padding -------------
__global__ __launch_bounds__(256) void fill_kernel(const int* __restrict__ barr,
                                                   const int* __restrict__ bbase,
                                                   const int* __restrict__ row_ptr,
                                                   int* __restrict__ csr, int N) {
    __shared__ int rbase[257];
    __shared__ int cur[256];
    int b = blockIdx.x;
    int n0 = b << 8;
    int nn = N - n0; if (nn > 256) nn = 256;
    int t = threadIdx.x;
    if (t < nn) { rbase[t] = row_ptr[n0 + t]; cur[t] = 0; }
    if (t == 0) rbase[nn] = row_ptr[n0 + nn];
    __syncthreads();
    int s0 = bbase[b], s1 = bbase[b + 1];
    for (int e = s0 + t; e < s1; e += 256) {
        int ed = barr[e];
        int d = ed >> 17;
        int r = atomicAdd(&cur[d], 1);
        csr[rbase[d] + r] = ed & 0x1FFFF;
    }
    __syncthreads();
    if (t < nn) {
        int p = rbase[t] + cur[t];
        int pe = rbase[t + 1];
        for (; p < pe; ++p) csr[p] = N;   // sentinel -> zero row Tb[N]
    }
}

// ------- GEMM: T'(bf16) = dinv[row] * (A @ W); thread=(row, quarter=waveId) ------------
__global__ __launch_bounds__(256) void gemm64_kernel(const float* __restrict__ A,
                                                     const float* __restrict__ W,
                                                     const float* __restrict__ dinv,
                                                     ushort16* __restrict__ Tb, int N) {
    int lane = threadIdx.x & 63;
    int q = __builtin_amdgcn_readfirstlane(threadIdx.x >> 6);   // wave-uniform quarter
    int row = blockIdx.x * 64 + lane;
    if (row >= N) return;
    const float4* arow = (const float4*)(A + (size_t)row * HDIM);
    const float* Wq = W + q * 16;
    float acc[16];
#pragma unroll
    for (int j = 0; j < 16; ++j) acc[j] = 0.f;
#pragma unroll 4
    for (int k4 = 0; k4 < 16; ++k4) {
        float4 a4 = arow[k4];
        const float* w0 = Wq + (k4 * 4) * HDIM;
#pragma unroll
        for (int j = 0; j < 16; ++j) acc[j] = fmaf(a4.x, w0[j], acc[j]);
#pragma unroll
        for (int j = 0; j < 16; ++j) acc[j] = fmaf(a4.y, w0[HDIM + j], acc[j]);
#pragma unroll
        for (int j = 0; j < 16; ++j) acc[j] = fmaf(a4.z, w0[2 * HDIM + j], acc[j]);
#pragma unroll
        for (int j = 0; j < 16; ++j) acc[j] = fmaf(a4.w, w0[3 * HDIM + j], acc[j]);
    }
    float di = dinv[row];
    uint4 o0, o1;
    o0.x = pack_bf16x2(acc[0] * di,  acc[1] * di);
    o0.y = pack_bf16x2(acc[2] * di,  acc[3] * di);
    o0.z = pack_bf16x2(acc[4] * di,  acc[5] * di);
    o0.w = pack_bf16x2(acc[6] * di,  acc[7] * di);
    o1.x = pack_bf16x2(acc[8] * di,  acc[9] * di);
    o1.y = pack_bf16x2(acc[10] * di, acc[11] * di);
    o1.z = pack_bf16x2(acc[12] * di, acc[13] * di);
    o1.w = pack_bf16x2(acc[14] * di, acc[15] * di);
    uint4* orow = (uint4*)(Tb + (size_t)row * HDIM + q * 16);
    orow[0] = o0;
    orow[1] = o1;
}

// ------- aggregate (R7 shape): 1 node/wave, 16-wide branch-free batches ----------------
__global__ __launch_bounds__(256) void aggregate_kernel(
    const ushort16* __restrict__ Tb, const float* __restrict__ dinv,
    const int* __restrict__ row_ptr, const int* __restrict__ csr,
    const float* __restrict__ bias, const float* __restrict__ gamma,
    const float* __restrict__ beta, const float* __restrict__ mean,
    const float* __restrict__ var,
    float* __restrict__ P, int N, int residual) {
    int node = (blockIdx.x * 256 + threadIdx.x) >> 6;
    int lane = threadIdx.x & 63;
    if (node >= N) return;
    int e = row_ptr[node], e1 = row_ptr[node + 1];
    float a0 = bf16_to_f32(Tb[(size_t)node * HDIM + lane]);  // self-loop term
    float a1 = 0.f, a2 = 0.f, a3 = 0.f;
    for (; e < e1; e += 16) {
        int4 s0 = *(const int4*)(csr + e);
        int4 s1 = *(const int4*)(csr + e + 4);
        int4 s2 = *(const int4*)(csr + e + 8);
        int4 s3 = *(const int4*)(csr + e + 12);
        float t0  = bf16_to_f32(Tb[(size_t)s0.x * HDIM + lane]);
        float t1  = bf16_to_f32(Tb[(size_t)s0.y * HDIM + lane]);
        float t2  = bf16_to_f32(Tb[(size_t)s0.z * HDIM + lane]);
        float t3  = bf16_to_f32(Tb[(size_t)s0.w * HDIM + lane]);
        float t4  = bf16_to_f32(Tb[(size_t)s1.x * HDIM + lane]);
        float t5  = bf16_to_f32(Tb[(size_t)s1.y * HDIM + lane]);
        float t6  = bf16_to_f32(Tb[(size_t)s1.z * HDIM + lane]);
        float t7  = bf16_to_f32(Tb[(size_t)s1.w * HDIM + lane]);
        float t8  = bf16_to_f32(Tb[(size_t)s2.x * HDIM + lane]);
        float t9  = bf16_to_f32(Tb[(size_t)s2.y * HDIM + lane]);
        float t10 = bf16_to_f32(Tb[(size_t)s2.z * HDIM + lane]);
        float t11 = bf16_to_f32(Tb[(size_t)s2.w * HDIM + lane]);
        float t12 = bf16_to_f32(Tb[(size_t)s3.x * HDIM + lane]);
        float t13 = bf16_to_f32(Tb[(size_t)s3.y * HDIM + lane]);
        float t14 = bf16_to_f32(Tb[(size_t)s3.z * HDIM + lane]);
        float t15 = bf16_to_f32(Tb[(size_t)s3.w * HDIM + lane]);
        a0 += t0 + t4;
        a1 += t1 + t5;
        a2 += t2 + t6;
        a3 += t3 + t7;
        a0 += t8 + t12;
        a1 += t9 + t13;
        a2 += t10 + t14;
        a3 += t11 + t15;
    }
    float acc = (a0 + a1) + (a2 + a3);
    float v = acc * dinv[node] + bias[lane];
    v = fmaxf(v, 0.f);
    v = (v - mean[lane]) * rsqrtf(var[lane] + 1e-5f) * gamma[lane] + beta[lane];
    if (residual) v += P[(size_t)node * HDIM + lane];
    P[(size_t)node * HDIM + lane] = v;
}

// ---------------- mean-pool ----------------
__global__ __launch_bounds__(256) void pool_kernel(const float* __restrict__ P,
                                                   const int* __restrict__ batch,
                                                   float* __restrict__ gsum,
                                                   float* __restrict__ gcnt, int N) {
    int wave = (blockIdx.x * 256 + threadIdx.x) >> 6;
    int lane = threadIdx.x & 63;
    int start = wave * 64;
    if (start >= N) return;
    int end = start + 64; if (end > N) end = N;
    float acc = 0.f;
    int cur = batch[start];
    int cnt = 0;
    for (int i = start; i < end; ++i) {
        int b = batch[i];
        if (b != cur) {
            atomicAdd(&gsum[cur * HDIM + lane], acc);
            if (lane == 0) atomicAdd(&gcnt[cur], (float)cnt);
            cur = b; acc = 0.f; cnt = 0;
        }
        acc += P[(size_t)i * HDIM + lane];
        cnt++;
    }
    atomicAdd(&gsum[cur * HDIM + lane], acc);
    if (lane == 0) atomicAdd(&gcnt[cur], (float)cnt);
}

// ---------------- MLP head (single block) ----------------
__global__ __launch_bounds__(256) void head_kernel(
    const float* __restrict__ gsum, const float* __restrict__ gcnt,
    const float* __restrict__ hW1, const float* __restrict__ hb1,
    const float* __restrict__ hgam, const float* __restrict__ hbet,
    const float* __restrict__ hm, const float* __restrict__ hv,
    const float* __restrict__ hW2, const float* __restrict__ hb2,
    float* __restrict__ out) {
    __shared__ float g[NGRAPH * HDIM];
    __shared__ float h1[NGRAPH * 32];
    int t = threadIdx.x;
    for (int idx = t; idx < NGRAPH * HDIM; idx += 256) {
        int gi = idx >> 6;
        g[idx] = gsum[idx] / fmaxf(gcnt[gi], 1.f);
    }
    __syncthreads();
    for (int idx = t; idx < NGRAPH * 32; idx += 256) {
        int gi = idx >> 5, j = idx & 31;
        float s = hb1[j];
#pragma unroll
        for (int f = 0; f < HDIM; ++f) s += g[gi * HDIM + f] * hW1[f * 32 + j];
        s = fmaxf(s, 0.f);
        s = (s - hm[j]) * rsqrtf(hv[j] + 1e-5f) * hgam[j] + hbet[j];
        h1[idx] = s;
    }
    __syncthreads();
    if (t < NGRAPH) {
        float s = hb2[0];
#pragma unroll
        for (int j = 0; j < 32; ++j) s += h1[t * 32 + j] * hW2[j];
        out[t] = s;
    }
}

static inline size_t align_up(size_t x) { return (x + 255) & ~(size_t)255; }

extern "C" void kernel_launch(void* const* d_in, const int* in_sizes, int n_in,
                              void* d_out, int out_size, void* d_ws, size_t ws_size,
                              hipStream_t stream) {
    const float* x    = (const float*)d_in[0];
    const int*   ei   = (const int*)d_in[1];
    const int*   batch= (const int*)d_in[2];
    const float* Wc   = (const float*)d_in[3];
    const float* bc   = (const float*)d_in[4];
    const float* bng  = (const float*)d_in[5];
    const float* bnb  = (const float*)d_in[6];
    const float* bnm  = (const float*)d_in[7];
    const float* bnv  = (const float*)d_in[8];
    const float* hW1  = (const float*)d_in[9];
    const float* hb1  = (const float*)d_in[10];
    const float* hgam = (const float*)d_in[11];
    const float* hbet = (const float*)d_in[12];
    const float* hm   = (const float*)d_in[13];
    const float* hv   = (const float*)d_in[14];
    const float* hW2  = (const float*)d_in[15];
    const float* hb2  = (const float*)d_in[16];
    float* out = (float*)d_out;

    const int N = in_sizes[0] / HDIM;   // 100000
    const int E = in_sizes[1] / 2;      // 1000000
    const int nbuck = (N + 255) >> 8;   // 391

    // ---- workspace carve (all 256B aligned) ----
    char* ws = (char*)d_ws;
    size_t off = 0;
    float*    P  = (float*)(ws + off);    off += align_up((size_t)N * HDIM * 4);
    ushort16* Tb = (ushort16*)(ws + off); off += align_up((size_t)(N + 1) * HDIM * 2); // +1 sentinel row
    int*   counts  = (int*)(ws + off);    off += align_up((size_t)N * 4);
    int*   row_ptr = (int*)(ws + off);    off += align_up((size_t)(N + 1) * 4);
    float* dinv    = (float*)(ws + off);  off += align_up((size_t)N * 4);
    int*   bsums   = (int*)(ws + off);    off += align_up(256 * 4);
    int*   bhist   = (int*)(ws + off);    off += align_up(512 * 4);
    int*   bbase   = (int*)(ws + off);    off += align_up(513 * 4);
    int*   bcursor = (int*)(ws + off);    off += align_up(512 * 4);
    float* gsum = (float*)(ws + off);
    float* gcnt = (float*)(ws + off + (size_t)NGRAPH * HDIM * 4);
    off += align_up((size_t)(NGRAPH * HDIM + NGRAPH) * 4);
    int*   barr = (int*)(ws + off);       off += align_up((size_t)E * 4);
    int*   csr  = (int*)(ws + off);       off += align_up(((size_t)E + (size_t)(PADM - 1) * N) * 4);

    int nScanBlocks = (N + SCAN_CHUNK - 1) / SCAN_CHUNK;   // 98
    int nPartBlocks = (E + EPB - 1) / EPB;                 // 245
    int gemmBlocks  = (N + 63) / 64;                       // 1563

    // ---- zero small state ----
    zero_kernel<<<2, 256, 0, stream>>>(bhist, nbuck);
    zero_kernel<<<(NGRAPH * HDIM + NGRAPH + 255) / 256, 256, 0, stream>>>((int*)gsum, NGRAPH * HDIM + NGRAPH);
    zero_kernel<<<1, 256, 0, stream>>>((int*)(Tb + (size_t)N * HDIM), 32);  // sentinel row = 0

    // ---- bucket partition + CSR build ----
    bucket_hist_kernel<<<nPartBlocks, 256, 0, stream>>>(ei, bhist, E, nbuck);
    bucket_scan_kernel<<<1, 512, 0, stream>>>(bhist, bbase, bcursor, nbuck);
    partition_kernel<<<nPartBlocks, 256, 0, stream>>>(ei, bcursor, barr, E, nbuck);
    degree_kernel<<<nbuck, 256, 0, stream>>>(barr, bbase, counts, N);
    bsum_kernel<<<nScanBlocks, 256, 0, stream>>>(counts, bsums, N);
    bscan_kernel<<<1, 256, 0, stream>>>(bsums, nScanBlocks, row_ptr, N);
    scan_apply_kernel<<<nScanBlocks, 256, 0, stream>>>(counts, bsums, row_ptr, dinv, N);
    fill_kernel<<<nbuck, 256, 0, stream>>>(barr, bbase, row_ptr, csr, N);

    // ---- 5 GCN layers ----
    int aggBlocks = (N + 3) / 4;   // 4 waves (nodes) per 256-thread block
    for (int l = 0; l < 5; ++l) {
        const float* in = (l == 0) ? x : P;
        gemm64_kernel<<<gemmBlocks, 256, 0, stream>>>(in, Wc + (size_t)l * HDIM * HDIM, dinv, Tb, N);
        aggregate_kernel<<<aggBlocks, 256, 0, stream>>>(
            Tb, dinv, row_ptr, csr,
            bc + l * HDIM, bng + l * HDIM, bnb + l * HDIM, bnm + l * HDIM, bnv + l * HDIM,
            P, N, (l > 0) ? 1 : 0);
    }

    // ---- pool + head ----
    int poolBlocks = (N + 255) / 256;
    pool_kernel<<<poolBlocks, 256, 0, stream>>>(P, batch, gsum, gcnt, N);
    head_kernel<<<1, 256, 0, stream>>>(gsum, gcnt, hW1, hb1, hgam, hbet, hm, hv, hW2, hb2, out);
}

// Round 11
// 475.123 us; speedup vs baseline: 1.1405x; 1.0091x over previous
//
#include <hip/hip_runtime.h>
#include <hip/hip_bf16.h>

// GCN: 5 x (GEMM 64x64 -> CSR gather + bias/ReLU/BN/residual) -> mean-pool -> MLP head.
// R2-R7: see history. R8/R9 (reverted): aggregate thruput = waves x inflight/wave;
//     R7 point (1 node/wave, 16 gathers in flight, 70% occ) is the optimum.
// R11: build-chain slimming: 1 fused zero kernel; degree emits per-bucket padded
//     totals -> 391-elem scan -> fill does per-node padded scan in LDS and writes
//     row_ptr+dinv+csr+sentinels in one pass. 12 launches -> 7 in the build phase.

#define NNODES 100000
#define NEDGES 1000000
#define NGRAPH 64
#define HDIM 64
#define PADM 16      // bucket pad multiple for aggregate's 16-wide batches
#define EPB 4096     // edges per block in partition phases

typedef unsigned int uint32;
typedef unsigned short ushort16;

__device__ __forceinline__ float bf16_to_f32(ushort16 u) {
    return __uint_as_float(((uint32)u) << 16);
}
__device__ __forceinline__ uint32 pack_bf16x2(float lo, float hi) {
    __hip_bfloat16 l = __float2bfloat16(lo);
    __hip_bfloat16 h = __float2bfloat16(hi);
    return ((uint32)(*(ushort16*)&h) << 16) | (uint32)(*(ushort16*)&l);
}
__device__ __forceinline__ int padded(int c) { return (c + PADM - 1) & ~(PADM - 1); }

// ---------------- fused zero: bhist | gsum+gcnt | Tb sentinel row ----------------
__global__ __launch_bounds__(256) void zero3_kernel(int* __restrict__ bhist, int nb,
                                                    int* __restrict__ gz, int ng,
                                                    int* __restrict__ sent, int ns) {
    int i = blockIdx.x * 256 + threadIdx.x;
    if (i < nb) bhist[i] = 0;
    if (i < ng) gz[i] = 0;
    if (i < ns) sent[i] = 0;
}

// ---------------- A1: bucket histogram (bucket = dst>>8) ----------------
__global__ __launch_bounds__(256) void bucket_hist_kernel(const int* __restrict__ ei,
                                                          int* __restrict__ bhist,
                                                          int E, int nbuck) {
    __shared__ int h[512];
    for (int i = threadIdx.x; i < nbuck; i += 256) h[i] = 0;
    __syncthreads();
    int base = blockIdx.x * EPB;
    int end = base + EPB; if (end > E) end = E;
    for (int e = base + threadIdx.x; e < end; e += 256)
        atomicAdd(&h[ei[E + e] >> 8], 1);
    __syncthreads();
    for (int i = threadIdx.x; i < nbuck; i += 256)
        if (h[i]) atomicAdd(&bhist[i], h[i]);
}

// ---------------- bucket scan: bases + cursors ----------------
__global__ __launch_bounds__(512) void bucket_scan_kernel(const int* __restrict__ bhist,
                                                          int* __restrict__ bbase,
                                                          int* __restrict__ bcursor,
                                                          int nbuck) {
    __shared__ int sh[512];
    int t = threadIdx.x;
    sh[t] = (t < nbuck) ? bhist[t] : 0;
    __syncthreads();
    for (int off = 1; off < 512; off <<= 1) {
        int v = (t >= off) ? sh[t - off] : 0;
        __syncthreads();
        sh[t] += v;
        __syncthreads();
    }
    int ex = (t == 0) ? 0 : sh[t - 1];
    if (t < nbuck) { bbase[t] = ex; bcursor[t] = ex; }
    if (t == nbuck) bbase[t] = sh[nbuck - 1];   // = E
}

// ------- A2: partition edges into bucket-contiguous packed ((d&255)<<17 | src) ---------
__global__ __launch_bounds__(256) void partition_kernel(const int* __restrict__ ei,
                                                        int* __restrict__ bcursor,
                                                        int* __restrict__ barr,
                                                        int E, int nbuck) {
    __shared__ int h[512];
    __shared__ int lbase[512];
    for (int i = threadIdx.x; i < nbuck; i += 256) h[i] = 0;
    __syncthreads();
    int base = blockIdx.x * EPB;
    int end = base + EPB; if (end > E) end = E;
    for (int e = base + threadIdx.x; e < end; e += 256)
        atomicAdd(&h[ei[E + e] >> 8], 1);
    __syncthreads();
    for (int i = threadIdx.x; i < nbuck; i += 256) {
        int c = h[i];
        lbase[i] = c ? atomicAdd(&bcursor[i], c) : 0;
        h[i] = 0;   // reuse as local cursor
    }
    __syncthreads();
    for (int e = base + threadIdx.x; e < end; e += 256) {
        int s = ei[e];
        int d = ei[E + e];
        int b = d >> 8;
        int r = atomicAdd(&h[b], 1);
        barr[lbase[b] + r] = ((d & 255) << 17) | s;
    }
}

// ------- B0: per-bucket degrees (LDS hist) + per-bucket PADDED total -------------------
__global__ __launch_bounds__(256) void degree_kernel(const int* __restrict__ barr,
                                                     const int* __restrict__ bbase,
                                                     int* __restrict__ counts,
                                                     int* __restrict__ ptotal, int N) {
    __shared__ int h[256];
    __shared__ int w4[4];
    int t = threadIdx.x;
    h[t] = 0;
    __syncthreads();
    int b = blockIdx.x;
    int s0 = bbase[b], s1 = bbase[b + 1];
    for (int e = s0 + t; e < s1; e += 256)
        atomicAdd(&h[barr[e] >> 17], 1);
    __syncthreads();
    int node = (b << 8) + t;
    int c = h[t];
    if (node < N) counts[node] = c; else c = 0;
    int p = padded(c);
    for (int off = 32; off > 0; off >>= 1) p += __shfl_down(p, off, 64);
    int lane = t & 63, wid = t >> 6;
    if (lane == 0) w4[wid] = p;
    __syncthreads();
    if (t == 0) ptotal[b] = w4[0] + w4[1] + w4[2] + w4[3];
}

// ---------------- scan of 391 per-bucket padded totals -> csr bucket bases -------------
__global__ __launch_bounds__(512) void cscan_kernel(const int* __restrict__ ptotal,
                                                    int* __restrict__ cbase,
                                                    int* __restrict__ row_ptr,
                                                    int nbuck, int N) {
    __shared__ int sh[512];
    int t = threadIdx.x;
    sh[t] = (t < nbuck) ? ptotal[t] : 0;
    __syncthreads();
    for (int off = 1; off < 512; off <<= 1) {
        int v = (t >= off) ? sh[t - off] : 0;
        __syncthreads();
        sh[t] += v;
        __syncthreads();
    }
    if (t < nbuck) cbase[t] = (t == 0) ? 0 : sh[t - 1];
    if (t == 0) row_ptr[N] = sh[nbuck - 1];   // total padded entries
}

// ------- B1 fused: per-node padded scan in LDS + row_ptr/dinv + counting-sort + pad ----
__global__ __launch_bounds__(256) void fill_kernel(const int* __restrict__ barr,
                                                   const int* __restrict__ bbase,
                                                   const int* __restrict__ counts,
                                                   const int* __restrict__ cbase,
                                                   int* __restrict__ row_ptr,
                                                   float* __restrict__ dinv,
                                                   int* __restrict__ csr, int N) {
    __shared__ int rbase[256];
    __shared__ int cur[256];
    __shared__ int sc[256];
    int b = blockIdx.x;
    int n0 = b << 8;
    int nn = N - n0; if (nn > 256) nn = 256;
    int t = threadIdx.x;
    int c = (t < nn) ? counts[n0 + t] : 0;
    int p = padded(c);
    sc[t] = p;
    __syncthreads();
    for (int off = 1; off < 256; off <<= 1) {
        int v = (t >= off) ? sc[t - off] : 0;
        __syncthreads();
        sc[t] += v;
        __syncthreads();
    }
    int rb = cbase[b] + sc[t] - p;   // exclusive
    rbase[t] = rb;
    cur[t] = 0;
    if (t < nn) {
        row_ptr[n0 + t] = rb;
        dinv[n0 + t] = rsqrtf((float)(c + 1));
    }
    __syncthreads();
    int s0 = bbase[b], s1 = bbase[b + 1];
    for (int e = s0 + t; e < s1; e += 256) {
        int ed = barr[e];
        int d = ed >> 17;
        int r = atomicAdd(&cur[d], 1);
        csr[rbase[d] + r] = ed & 0x1FFFF;
    }
    __syncthreads();
    if (t < nn) {
        int q = rbase[t] + c;
        int pe = rbase[t] + p;
        for (; q < pe; ++q) csr[q] = N;   // sentinel -> zero row Tb[N]
    }
}

// ------- GEMM: T'(bf16) = dinv[row] * (A @ W); thread=(row, quarter=waveId) ------------
__global__ __launch_bounds__(256) void gemm64_kernel(const float* __restrict__ A,
                                                     const float* __restrict__ W,
                                                     const float* __restrict__ dinv,
                                                     ushort16* __restrict__ Tb, int N) {
    int lane = threadIdx.x & 63;
    int q = __builtin_amdgcn_readfirstlane(threadIdx.x >> 6);   // wave-uniform quarter
    int row = blockIdx.x * 64 + lane;
    if (row >= N) return;
    const float4* arow = (const float4*)(A + (size_t)row * HDIM);
    const float* Wq = W + q * 16;
    float acc[16];
#pragma unroll
    for (int j = 0; j < 16; ++j) acc[j] = 0.f;
#pragma unroll 4
    for (int k4 = 0; k4 < 16; ++k4) {
        float4 a4 = arow[k4];
        const float* w0 = Wq + (k4 * 4) * HDIM;
#pragma unroll
        for (int j = 0; j < 16; ++j) acc[j] = fmaf(a4.x, w0[j], acc[j]);
#pragma unroll
        for (int j = 0; j < 16; ++j) acc[j] = fmaf(a4.y, w0[HDIM + j], acc[j]);
#pragma unroll
        for (int j = 0; j < 16; ++j) acc[j] = fmaf(a4.z, w0[2 * HDIM + j], acc[j]);
#pragma unroll
        for (int j = 0; j < 16; ++j) acc[j] = fmaf(a4.w, w0[3 * HDIM + j], acc[j]);
    }
    float di = dinv[row];
    uint4 o0, o1;
    o0.x = pack_bf16x2(acc[0] * di,  acc[1] * di);
    o0.y = pack_bf16x2(acc[2] * di,  acc[3] * di);
    o0.z = pack_bf16x2(acc[4] * di,  acc[5] * di);
    o0.w = pack_bf16x2(acc[6] * di,  acc[7] * di);
    o1.x = pack_bf16x2(acc[8] * di,  acc[9] * di);
    o1.y = pack_bf16x2(acc[10] * di, acc[11] * di);
    o1.z = pack_bf16x2(acc[12] * di, acc[13] * di);
    o1.w = pack_bf16x2(acc[14] * di, acc[15] * di);
    uint4* orow = (uint4*)(Tb + (size_t)row * HDIM + q * 16);
    orow[0] = o0;
    orow[1] = o1;
}

// ------- aggregate (R7 shape): 1 node/wave, 16-wide branch-free batches ----------------
__global__ __launch_bounds__(256) void aggregate_kernel(
    const ushort16* __restrict__ Tb, const float* __restrict__ dinv,
    const int* __restrict__ row_ptr, const int* __restrict__ csr,
    const float* __restrict__ bias, const float* __restrict__ gamma,
    const float* __restrict__ beta, const float* __restrict__ mean,
    const float* __restrict__ var,
    float* __restrict__ P, int N, int residual) {
    int node = (blockIdx.x * 256 + threadIdx.x) >> 6;
    int lane = threadIdx.x & 63;
    if (node >= N) return;
    int e = row_ptr[node], e1 = row_ptr[node + 1];
    float a0 = bf16_to_f32(Tb[(size_t)node * HDIM + lane]);  // self-loop term
    float a1 = 0.f, a2 = 0.f, a3 = 0.f;
    for (; e < e1; e += 16) {
        int4 s0 = *(const int4*)(csr + e);
        int4 s1 = *(const int4*)(csr + e + 4);
        int4 s2 = *(const int4*)(csr + e + 8);
        int4 s3 = *(const int4*)(csr + e + 12);
        float t0  = bf16_to_f32(Tb[(size_t)s0.x * HDIM + lane]);
        float t1  = bf16_to_f32(Tb[(size_t)s0.y * HDIM + lane]);
        float t2  = bf16_to_f32(Tb[(size_t)s0.z * HDIM + lane]);
        float t3  = bf16_to_f32(Tb[(size_t)s0.w * HDIM + lane]);
        float t4  = bf16_to_f32(Tb[(size_t)s1.x * HDIM + lane]);
        float t5  = bf16_to_f32(Tb[(size_t)s1.y * HDIM + lane]);
        float t6  = bf16_to_f32(Tb[(size_t)s1.z * HDIM + lane]);
        float t7  = bf16_to_f32(Tb[(size_t)s1.w * HDIM + lane]);
        float t8  = bf16_to_f32(Tb[(size_t)s2.x * HDIM + lane]);
        float t9  = bf16_to_f32(Tb[(size_t)s2.y * HDIM + lane]);
        float t10 = bf16_to_f32(Tb[(size_t)s2.z * HDIM + lane]);
        float t11 = bf16_to_f32(Tb[(size_t)s2.w * HDIM + lane]);
        float t12 = bf16_to_f32(Tb[(size_t)s3.x * HDIM + lane]);
        float t13 = bf16_to_f32(Tb[(size_t)s3.y * HDIM + lane]);
        float t14 = bf16_to_f32(Tb[(size_t)s3.z * HDIM + lane]);
        float t15 = bf16_to_f32(Tb[(size_t)s3.w * HDIM + lane]);
        a0 += t0 + t4;
        a1 += t1 + t5;
        a2 += t2 + t6;
        a3 += t3 + t7;
        a0 += t8 + t12;
        a1 += t9 + t13;
        a2 += t10 + t14;
        a3 += t11 + t15;
    }
    float acc = (a0 + a1) + (a2 + a3);
    float v = acc * dinv[node] + bias[lane];
    v = fmaxf(v, 0.f);
    v = (v - mean[lane]) * rsqrtf(var[lane] + 1e-5f) * gamma[lane] + beta[lane];
    if (residual) v += P[(size_t)node * HDIM + lane];
    P[(size_t)node * HDIM + lane] = v;
}

// ---------------- mean-pool ----------------
__global__ __launch_bounds__(256) void pool_kernel(const float* __restrict__ P,
                                                   const int* __restrict__ batch,
                                                   float* __restrict__ gsum,
                                                   float* __restrict__ gcnt, int N) {
    int wave = (blockIdx.x * 256 + threadIdx.x) >> 6;
    int lane = threadIdx.x & 63;
    int start = wave * 64;
    if (start >= N) return;
    int end = start + 64; if (end > N) end = N;
    float acc = 0.f;
    int cur = batch[start];
    int cnt = 0;
    for (int i = start; i < end; ++i) {
        int b = batch[i];
        if (b != cur) {
            atomicAdd(&gsum[cur * HDIM + lane], acc);
            if (lane == 0) atomicAdd(&gcnt[cur], (float)cnt);
            cur = b; acc = 0.f; cnt = 0;
        }
        acc += P[(size_t)i * HDIM + lane];
        cnt++;
    }
    atomicAdd(&gsum[cur * HDIM + lane], acc);
    if (lane == 0) atomicAdd(&gcnt[cur], (float)cnt);
}

// ---------------- MLP head (single block) ----------------
__global__ __launch_bounds__(256) void head_kernel(
    const float* __restrict__ gsum, const float* __restrict__ gcnt,
    const float* __restrict__ hW1, const float* __restrict__ hb1,
    const float* __restrict__ hgam, const float* __restrict__ hbet,
    const float* __restrict__ hm, const float* __restrict__ hv,
    const float* __restrict__ hW2, const float* __restrict__ hb2,
    float* __restrict__ out) {
    __shared__ float g[NGRAPH * HDIM];
    __shared__ float h1[NGRAPH * 32];
    int t = threadIdx.x;
    for (int idx = t; idx < NGRAPH * HDIM; idx += 256) {
        int gi = idx >> 6;
        g[idx] = gsum[idx] / fmaxf(gcnt[gi], 1.f);
    }
    __syncthreads();
    for (int idx = t; idx < NGRAPH * 32; idx += 256) {
        int gi = idx >> 5, j = idx & 31;
        float s = hb1[j];
#pragma unroll
        for (int f = 0; f < HDIM; ++f) s += g[gi * HDIM + f] * hW1[f * 32 + j];
        s = fmaxf(s, 0.f);
        s = (s - hm[j]) * rsqrtf(hv[j] + 1e-5f) * hgam[j] + hbet[j];
        h1[idx] = s;
    }
    __syncthreads();
    if (t < NGRAPH) {
        float s = hb2[0];
#pragma unroll
        for (int j = 0; j < 32; ++j) s += h1[t * 32 + j] * hW2[j];
        out[t] = s;
    }
}

static inline size_t align_up(size_t x) { return (x + 255) & ~(size_t)255; }

extern "C" void kernel_launch(void* const* d_in, const int* in_sizes, int n_in,
                              void* d_out, int out_size, void* d_ws, size_t ws_size,
                              hipStream_t stream) {
    const float* x    = (const float*)d_in[0];
    const int*   ei   = (const int*)d_in[1];
    const int*   batch= (const int*)d_in[2];
    const float* Wc   = (const float*)d_in[3];
    const float* bc   = (const float*)d_in[4];
    const float* bng  = (const float*)d_in[5];
    const float* bnb  = (const float*)d_in[6];
    const float* bnm  = (const float*)d_in[7];
    const float* bnv  = (const float*)d_in[8];
    const float* hW1  = (const float*)d_in[9];
    const float* hb1  = (const float*)d_in[10];
    const float* hgam = (const float*)d_in[11];
    const float* hbet = (const float*)d_in[12];
    const float* hm   = (const float*)d_in[13];
    const float* hv   = (const float*)d_in[14];
    const float* hW2  = (const float*)d_in[15];
    const float* hb2  = (const float*)d_in[16];
    float* out = (float*)d_out;

    const int N = in_sizes[0] / HDIM;   // 100000
    const int E = in_sizes[1] / 2;      // 1000000
    const int nbuck = (N + 255) >> 8;   // 391

    // ---- workspace carve (all 256B aligned) ----
    char* ws = (char*)d_ws;
    size_t off = 0;
    float*    P  = (float*)(ws + off);    off += align_up((size_t)N * HDIM * 4);
    ushort16* Tb = (ushort16*)(ws + off); off += align_up((size_t)(N + 1) * HDIM * 2); // +1 sentinel row
    int*   counts  = (int*)(ws + off);    off += align_up((size_t)N * 4);
    int*   row_ptr = (int*)(ws + off);    off += align_up((size_t)(N + 1) * 4);
    float* dinv    = (float*)(ws + off);  off += align_up((size_t)N * 4);
    int*   bhist   = (int*)(ws + off);    off += align_up(512 * 4);
    int*   bbase   = (int*)(ws + off);    off += align_up(513 * 4);
    int*   bcursor = (int*)(ws + off);    off += align_up(512 * 4);
    int*   ptotal  = (int*)(ws + off);    off += align_up(512 * 4);
    int*   cbase   = (int*)(ws + off);    off += align_up(512 * 4);
    float* gsum = (float*)(ws + off);
    float* gcnt = (float*)(ws + off + (size_t)NGRAPH * HDIM * 4);
    off += align_up((size_t)(NGRAPH * HDIM + NGRAPH) * 4);
    int*   barr = (int*)(ws + off);       off += align_up((size_t)E * 4);
    int*   csr  = (int*)(ws + off);       off += align_up(((size_t)E + (size_t)(PADM - 1) * N) * 4);

    int nPartBlocks = (E + EPB - 1) / EPB;                 // 245
    int gemmBlocks  = (N + 63) / 64;                       // 1563
    int nZero = NGRAPH * HDIM + NGRAPH;                    // 4160

    // ---- fused zero (bhist | gsum+gcnt | sentinel row) ----
    zero3_kernel<<<(nZero + 255) / 256, 256, 0, stream>>>(
        bhist, nbuck, (int*)gsum, nZero, (int*)(Tb + (size_t)N * HDIM), 32);

    // ---- bucket partition + fused CSR build ----
    bucket_hist_kernel<<<nPartBlocks, 256, 0, stream>>>(ei, bhist, E, nbuck);
    bucket_scan_kernel<<<1, 512, 0, stream>>>(bhist, bbase, bcursor, nbuck);
    partition_kernel<<<nPartBlocks, 256, 0, stream>>>(ei, bcursor, barr, E, nbuck);
    degree_kernel<<<nbuck, 256, 0, stream>>>(barr, bbase, counts, ptotal, N);
    cscan_kernel<<<1, 512, 0, stream>>>(ptotal, cbase, row_ptr, nbuck, N);
    fill_kernel<<<nbuck, 256, 0, stream>>>(barr, bbase, counts, cbase, row_ptr, dinv, csr, N);

    // ---- 5 GCN layers ----
    int aggBlocks = (N + 3) / 4;   // 4 waves (nodes) per 256-thread block
    for (int l = 0; l < 5; ++l) {
        const float* in = (l == 0) ? x : P;
        gemm64_kernel<<<gemmBlocks, 256, 0, stream>>>(in, Wc + (size_t)l * HDIM * HDIM, dinv, Tb, N);
        aggregate_kernel<<<aggBlocks, 256, 0, stream>>>(
            Tb, dinv, row_ptr, csr,
            bc + l * HDIM, bng + l * HDIM, bnb + l * HDIM, bnm + l * HDIM, bnv + l * HDIM,
            P, N, (l > 0) ? 1 : 0);
    }

    // ---- pool + head ----
    int poolBlocks = (N + 255) / 256;
    pool_kernel<<<poolBlocks, 256, 0, stream>>>(P, batch, gsum, gcnt, N);
    head_kernel<<<1, 256, 0, stream>>>(gsum, gcnt, hW1, hb1, hgam, hbet, hm, hv, hW2, hb2, out);
}